// Round 5
// baseline (1147.115 us; speedup 1.0000x reference)
//
#include <hip/hip_runtime.h>

#define N_NODES 10000
#define N_EDGES 50000
#define IN0     32
#define EDGE_IN 16
#define GIN     8
#define HID     64
#define NG      64
#define KDIM    128
#define EPS     1e-5f
#define KSPLIT  4
#define BPAD    70   // Bs row stride in halfs: bank = (3m+4q)%32 -> max 2-way (free)

typedef _Float16 f16;
typedef _Float16 v8h __attribute__((ext_vector_type(8)));
typedef float    v4f __attribute__((ext_vector_type(4)));

// ---------------------------------------------------------------------------
// ht[j][e] = f16(relu(ea[e]@w1[:,j] + b1[j]))  -- transposed for the fused GEMM
__global__ __launch_bounds__(256) void ht_kernel(const float* __restrict__ ea,
                                                 const float* __restrict__ w1,
                                                 const float* __restrict__ b1,
                                                 f16* __restrict__ ht) {
    __shared__ float eas[256][17];
    const int e0 = blockIdx.x * 256, t = threadIdx.x;
    for (int idx = t; idx < 256 * 16; idx += 256) {
        int r = idx >> 4, i = idx & 15;
        eas[r][i] = (e0 + r < N_EDGES) ? ea[(size_t)(e0 + r) * EDGE_IN + i] : 0.f;
    }
    __syncthreads();
    const int e = e0 + t;
#pragma unroll 1
    for (int j = 0; j < KDIM; j++) {
        float acc = b1[j];
#pragma unroll
        for (int i = 0; i < EDGE_IN; i++) acc += eas[t][i] * w1[i * KDIM + j];
        if (e < N_EDGES) ht[(size_t)j * N_EDGES + e] = (f16)fmaxf(acc, 0.f);
    }
}

// ---------------------------------------------------------------------------
// xf[idx] = f16(x[idx])
__global__ __launch_bounds__(256) void xconv(const float* __restrict__ x,
                                             f16* __restrict__ xf, int n) {
    int idx = blockIdx.x * 256 + threadIdx.x;
    if (idx < n) xf[idx] = (f16)x[idx];
}

// ---------------------------------------------------------------------------
// Bg[chunk][o][cc] = f16 of B[C=chunk*64+cc, o] where B[k*in+i, o]=w2[k][i*64+o],
// B[in*128+i, o]=b2[i*64+o], else 0.  (chunk = 64 K-rows of the flattened GEMM)
__global__ __launch_bounds__(256) void bconv(const float* __restrict__ w2,
                                             const float* __restrict__ b2,
                                             f16* __restrict__ Bg,
                                             int in, int inshift) {
    const int chunk = blockIdx.x;
    const int inK = in << 7;
    const size_t base = (size_t)chunk * 4096;
    for (int l = threadIdx.x; l < 4096; l += 256) {
        int o = l >> 6, cc = l & 63;
        int C = (chunk << 6) + cc;
        float v = 0.f;
        if (C < inK) {
            int k = C >> inshift, i = C & (in - 1);
            v = w2[(size_t)k * (in << 6) + (i << 6) + o];
        } else if (C < inK + in) {
            v = b2[((C - inK) << 6) + o];
        }
        Bg[base + l] = (f16)v;
    }
}

// ---------------------------------------------------------------------------
// Fused NNConv message+scatter:  agg[dst[e],o] += sum_C (h[e,k]*x[src,i]) * B[C,o]
// M=256 edges/block (4 waves x 64), N=64, K streamed in 64-chunks via LDS dbuf.
// grid.y = KSPLIT partitions of the chunk range (partials merged via atomics).
__global__ __launch_bounds__(256) void fused_msg(const f16* __restrict__ ht,
                                                 const f16* __restrict__ xf,
                                                 const f16* __restrict__ Bg,
                                                 const int* __restrict__ src,
                                                 const int* __restrict__ dst,
                                                 float* __restrict__ agg,
                                                 int in, int inshift, int nch) {
    __shared__ f16 Bs[2][64 * BPAD];
    __shared__ int dst_l[256];
    const int t = threadIdx.x;
    const int w = t >> 6, lane = t & 63;
    const int m = lane & 15, q = lane >> 4;
    const int e0 = blockIdx.x * 256;
    const int inK = in << 7;
    const int cbeg = (nch * (int)blockIdx.y) / KSPLIT;
    const int cend = (nch * ((int)blockIdx.y + 1)) / KSPLIT;

    dst_l[t] = (e0 + t < N_EDGES) ? dst[e0 + t] : -1;

    // per-lane x fragments: x[v_s][p*32 + q*8 .. +7], fixed for whole K loop
    v8h xr[4][2];
    int eidx[4];
#pragma unroll
    for (int s = 0; s < 4; s++) {
        int e = e0 + w * 64 + s * 16 + m;
        eidx[s] = e < N_EDGES ? e : N_EDGES - 1;
        const f16* xrow = xf + (size_t)src[eidx[s]] * in;
        xr[s][0] = *(const v8h*)(xrow + q * 8);
        if (in == 64) xr[s][1] = *(const v8h*)(xrow + 32 + q * 8);
        else          xr[s][1] = xr[s][0];
    }

    // B staging geometry: thread copies 16 f16 (32B): row so, segment sseg
    const int so = t >> 2, sseg = t & 3;
    const size_t goff = (size_t)so * 64 + sseg * 16;
    const int    loff = so * BPAD + sseg * 16;
    {
        const uint4* gp = (const uint4*)(Bg + (size_t)cbeg * 4096 + goff);
        *((uint4*)(&Bs[0][loff]))     = gp[0];
        *((uint4*)(&Bs[0][loff + 8])) = gp[1];
    }
    __syncthreads();

    v4f acc[4][4] = {};
    int buf = 0;
    for (int c = cbeg; c < cend; c++) {
        uint4 r0, r1;
        const bool pf = (c + 1 < cend);
        if (pf) {
            const uint4* gp = (const uint4*)(Bg + (size_t)(c + 1) * 4096 + goff);
            r0 = gp[0]; r1 = gp[1];
        }
        const f16* bb = Bs[buf];
#pragma unroll
        for (int p = 0; p < 2; p++) {
            const int c0 = (c << 6) + (p << 5);
            if (c0 < inK + in) {
                const int xs = p & (in >> 6);   // 64->p, 32->0
                f16 hv[4];
                if (c0 < inK) {
                    const int k = c0 >> inshift;
                    const f16* hp = ht + (size_t)k * N_EDGES;
#pragma unroll
                    for (int s = 0; s < 4; s++) hv[s] = hp[eidx[s]];
                } else {
#pragma unroll
                    for (int s = 0; s < 4; s++) hv[s] = (f16)1.0f;
                }
                v8h bf[4];
#pragma unroll
                for (int tt = 0; tt < 4; tt++)
                    bf[tt] = *(const v8h*)(bb + (tt * 16 + m) * BPAD + p * 32 + q * 8);
#pragma unroll
                for (int s = 0; s < 4; s++) {
                    v8h af;
#pragma unroll
                    for (int j = 0; j < 8; j++) af[j] = xr[s][xs][j] * hv[s];
#pragma unroll
                    for (int tt = 0; tt < 4; tt++)
                        acc[s][tt] = __builtin_amdgcn_mfma_f32_16x16x32_f16(
                            af, bf[tt], acc[s][tt], 0, 0, 0);
                }
            }
        }
        if (pf) {
            *((uint4*)(&Bs[buf ^ 1][loff]))     = r0;
            *((uint4*)(&Bs[buf ^ 1][loff + 8])) = r1;
        }
        __syncthreads();
        buf ^= 1;
    }

    // epilogue: C/D layout col=lane&15, row=quad*4+reg
#pragma unroll
    for (int s = 0; s < 4; s++) {
        const int el = w * 64 + s * 16 + q * 4;
#pragma unroll
        for (int r = 0; r < 4; r++) {
            const int d = dst_l[el + r];
            if (d >= 0) {
#pragma unroll
                for (int tt = 0; tt < 4; tt++)
                    atomicAdd(&agg[(size_t)d * 64 + tt * 16 + m], acc[s][tt][r]);
            }
        }
    }
}

// ---------------------------------------------------------------------------
// pre[n,o] = agg[n,o] + sum_i x[n,i]*root[i,o] + bias[o]; accumulate BN stats.
__global__ __launch_bounds__(256) void pre_stats(const float* __restrict__ agg,
                                                 const float* __restrict__ x,
                                                 const float* __restrict__ root,
                                                 const float* __restrict__ bias,
                                                 float* __restrict__ pre,
                                                 float* __restrict__ stats,
                                                 int in, int inshift) {
    __shared__ float xs[4][64];
    __shared__ float lsum[64], lsq[64];
    const int o = threadIdx.x & 63, nl = threadIdx.x >> 6;
    if (threadIdx.x < 64) { lsum[threadIdx.x] = 0.f; lsq[threadIdx.x] = 0.f; }
    const float bo = bias[o];
    for (int n0 = blockIdx.x * 4; n0 < N_NODES; n0 += gridDim.x * 4) {
        __syncthreads();
        for (int idx = threadIdx.x; idx < (4 << inshift); idx += 256) {
            int r = idx >> inshift, i = idx & (in - 1);
            if (n0 + r < N_NODES) xs[r][i] = x[(size_t)(n0 + r) * in + i];
        }
        __syncthreads();
        int n = n0 + nl;
        if (n < N_NODES) {
            float acc = agg[(size_t)n * 64 + o] + bo;
#pragma unroll 8
            for (int i = 0; i < in; i++) acc += xs[nl][i] * root[i * 64 + o];
            pre[(size_t)n * 64 + o] = acc;
            atomicAdd(&lsum[o], acc);
            atomicAdd(&lsq[o], acc * acc);
        }
    }
    __syncthreads();
    if (threadIdx.x < 64) {
        atomicAdd(&stats[threadIdx.x], lsum[threadIdx.x]);
        atomicAdd(&stats[64 + threadIdx.x], lsq[threadIdx.x]);
    }
}

// ---------------------------------------------------------------------------
// BN (batch stats, biased var) + ReLU. mode 0: store xn. mode 1: segment-max pool.
__global__ __launch_bounds__(256) void bn_apply(const float* __restrict__ pre,
                                                const float* __restrict__ stats,
                                                const float* __restrict__ gamma,
                                                const float* __restrict__ beta,
                                                float* __restrict__ xn,
                                                const int* __restrict__ batch,
                                                float* __restrict__ pooled,
                                                int mode) {
    int idx = blockIdx.x * 256 + threadIdx.x;
    if (idx >= N_NODES * 64) return;
    const int o = idx & 63, n = idx >> 6;
    const float inv = 1.f / (float)N_NODES;
    float mu = stats[o] * inv;
    float var = stats[64 + o] * inv - mu * mu;
    float sc = gamma[o] * rsqrtf(var + EPS);
    float sh = beta[o] - mu * sc;
    float v = fmaxf(pre[idx] * sc + sh, 0.f);
    if (mode == 0) xn[idx] = v;
    else atomicMax((int*)&pooled[(size_t)batch[n] * 64 + o], __float_as_int(v));
}

// ---------------------------------------------------------------------------
// out[g] = pp_b2 + relu(cat(pooled[g],u[g]) @ pp_w1 + pp_b1) @ pp_w2
__global__ __launch_bounds__(64) void final_mlp(const float* __restrict__ pooled,
                                                const float* __restrict__ u,
                                                const float* __restrict__ w1,
                                                const float* __restrict__ b1,
                                                const float* __restrict__ w2,
                                                const float* __restrict__ b2,
                                                float* __restrict__ out) {
    const int g = blockIdx.x, t = threadIdx.x;
    float acc = b1[t];
#pragma unroll 8
    for (int i = 0; i < 64; i++) acc += pooled[g * 64 + i] * w1[i * 64 + t];
#pragma unroll
    for (int j = 0; j < GIN; j++) acc += u[g * GIN + j] * w1[(64 + j) * 64 + t];
    float hv = fmaxf(acc, 0.f) * w2[t];
#pragma unroll
    for (int off = 32; off > 0; off >>= 1) hv += __shfl_down(hv, off, 64);
    if (t == 0) out[g] = hv + b2[0];
}

// ---------------------------------------------------------------------------
extern "C" void kernel_launch(void* const* d_in, const int* in_sizes, int n_in,
                              void* d_out, int out_size, void* d_ws, size_t ws_size,
                              hipStream_t stream) {
    const float* x0      = (const float*)d_in[0];
    const int*   ei      = (const int*)d_in[1];
    const int*   src     = ei;
    const int*   dst     = ei + N_EDGES;
    const float* ea      = (const float*)d_in[2];
    const int*   batch   = (const int*)d_in[3];
    const float* u       = (const float*)d_in[4];
    const float* e0w1    = (const float*)d_in[5];
    const float* e0b1    = (const float*)d_in[6];
    const float* e0w2    = (const float*)d_in[7];
    const float* e0b2    = (const float*)d_in[8];
    const float* root0   = (const float*)d_in[9];
    const float* bias0   = (const float*)d_in[10];
    const float* gamma0  = (const float*)d_in[11];
    const float* beta0   = (const float*)d_in[12];
    const float* ew1     = (const float*)d_in[13];
    const float* eb1     = (const float*)d_in[14];
    const float* ew2     = (const float*)d_in[15];
    const float* eb2     = (const float*)d_in[16];
    const float* rootl   = (const float*)d_in[17];
    const float* biasl   = (const float*)d_in[18];
    const float* gammal  = (const float*)d_in[19];
    const float* betal   = (const float*)d_in[20];
    const float* pp_w1   = (const float*)d_in[21];
    const float* pp_b1   = (const float*)d_in[22];
    const float* pp_w2   = (const float*)d_in[23];
    const float* pp_b2   = (const float*)d_in[24];

    float* ws = (float*)d_ws;
    size_t off = 0;
    f16*   ht     = (f16*)(ws + off); off += (size_t)N_EDGES * KDIM / 2;
    f16*   xf     = (f16*)(ws + off); off += (size_t)N_NODES * 64 / 2;
    f16*   Bg     = (f16*)(ws + off); off += (size_t)129 * 4096 / 2;
    float* agg    = ws + off; off += (size_t)N_NODES * 64;
    float* xa     = ws + off; off += (size_t)N_NODES * 64;
    float* xb     = ws + off; off += (size_t)N_NODES * 64;
    float* stats  = ws + off; off += 256;
    float* pooled = ws + off; off += (size_t)NG * 64;

    hipMemsetAsync(pooled, 0, (size_t)NG * 64 * 4, stream);

    struct Layer {
        const float *w1, *b1, *w2, *b2, *root, *bias, *gamma, *beta, *xin;
        float* xout; int in, inshift, mode;
    };
    Layer L[4];
    L[0] = {e0w1, e0b1, e0w2, e0b2, root0, bias0, gamma0, beta0, x0, xa, IN0, 5, 0};
    for (int l = 0; l < 3; l++) {
        const float* xin  = (l == 0) ? xa : ((l == 1) ? xb : xa);
        float*       xout = (l == 0) ? xb : ((l == 1) ? xa : nullptr);
        L[l + 1] = {ew1 + (size_t)l * EDGE_IN * KDIM, eb1 + (size_t)l * KDIM,
                    ew2 + (size_t)l * KDIM * (HID * HID), eb2 + (size_t)l * (HID * HID),
                    rootl + (size_t)l * HID * HID, biasl + (size_t)l * HID,
                    gammal + (size_t)l * HID, betal + (size_t)l * HID,
                    xin, xout, HID, 6, (l == 2) ? 1 : 0};
    }

    const int eblocks = (N_EDGES + 255) / 256;               // 196
    const int ablocks = (N_NODES * 64 + 255) / 256;

    for (int l = 0; l < 4; l++) {
        const Layer& P = L[l];
        const int nch = (P.in * 129 + 63) / 64;              // 65 (in=32) / 129 (in=64)
        ht_kernel<<<eblocks, 256, 0, stream>>>(ea, P.w1, P.b1, ht);
        xconv<<<(N_NODES * P.in + 255) / 256, 256, 0, stream>>>(P.xin, xf, N_NODES * P.in);
        bconv<<<nch, 256, 0, stream>>>(P.w2, P.b2, Bg, P.in, P.inshift);
        hipMemsetAsync(agg, 0, (size_t)N_NODES * 64 * 4, stream);
        hipMemsetAsync(stats, 0, 128 * 4, stream);
        fused_msg<<<dim3(eblocks, KSPLIT), 256, 0, stream>>>(ht, xf, Bg, src, dst, agg,
                                                             P.in, P.inshift, nch);
        pre_stats<<<512, 256, 0, stream>>>(agg, P.xin, P.root, P.bias, agg, stats,
                                           P.in, P.inshift);
        bn_apply<<<ablocks, 256, 0, stream>>>(agg, stats, P.gamma, P.beta, P.xout,
                                              batch, pooled, P.mode);
    }
    final_mlp<<<NG, 64, 0, stream>>>(pooled, u, pp_w1, pp_b1, pp_w2, pp_b2,
                                     (float*)d_out);
}

// Round 6
// 1030.101 us; speedup vs baseline: 1.1136x; 1.1136x over previous
//
#include <hip/hip_runtime.h>

#define N_NODES 10000
#define N_EDGES 50000
#define IN0     32
#define EDGE_IN 16
#define GIN     8
#define HID     64
#define NG      64
#define KDIM    128
#define EPS     1e-5f
#define KSPLIT  4
#define BPAD    70   // Bs row stride in halfs: read bank = (3m+4q)%32 -> max 2-way (free)

typedef _Float16 f16;
typedef _Float16 v8h __attribute__((ext_vector_type(8)));
typedef float    v4f __attribute__((ext_vector_type(4)));

// ---------------------------------------------------------------------------
// ht[j][e] = f16(relu(ea[e]@w1[:,j] + b1[j]))  -- transposed for the fused GEMM
__global__ __launch_bounds__(256) void ht_kernel(const float* __restrict__ ea,
                                                 const float* __restrict__ w1,
                                                 const float* __restrict__ b1,
                                                 f16* __restrict__ ht) {
    __shared__ float eas[256][17];
    const int e0 = blockIdx.x * 256, t = threadIdx.x;
    for (int idx = t; idx < 256 * 16; idx += 256) {
        int r = idx >> 4, i = idx & 15;
        eas[r][i] = (e0 + r < N_EDGES) ? ea[(size_t)(e0 + r) * EDGE_IN + i] : 0.f;
    }
    __syncthreads();
    const int e = e0 + t;
#pragma unroll 1
    for (int j = 0; j < KDIM; j++) {
        float acc = b1[j];
#pragma unroll
        for (int i = 0; i < EDGE_IN; i++) acc += eas[t][i] * w1[i * KDIM + j];
        if (e < N_EDGES) ht[(size_t)j * N_EDGES + e] = (f16)fmaxf(acc, 0.f);
    }
}

// ---------------------------------------------------------------------------
// xf[idx] = f16(x[idx])
__global__ __launch_bounds__(256) void xconv(const float* __restrict__ x,
                                             f16* __restrict__ xf, int n) {
    int idx = blockIdx.x * 256 + threadIdx.x;
    if (idx < n) xf[idx] = (f16)x[idx];
}

// ---------------------------------------------------------------------------
// Bg[chunk][o][cc] = f16 of B[C=chunk*64+cc, o] where B[k*in+i, o]=w2[k][i*64+o],
// B[in*128+i, o]=b2[i*64+o], else 0.
__global__ __launch_bounds__(256) void bconv(const float* __restrict__ w2,
                                             const float* __restrict__ b2,
                                             f16* __restrict__ Bg,
                                             int in, int inshift) {
    const int chunk = blockIdx.x;
    const int inK = in << 7;
    const size_t base = (size_t)chunk * 4096;
    for (int l = threadIdx.x; l < 4096; l += 256) {
        int o = l >> 6, cc = l & 63;
        int C = (chunk << 6) + cc;
        float v = 0.f;
        if (C < inK) {
            int k = C >> inshift, i = C & (in - 1);
            v = w2[(size_t)k * (in << 6) + (i << 6) + o];
        } else if (C < inK + in) {
            v = b2[((C - inK) << 6) + o];
        }
        Bg[base + l] = (f16)v;
    }
}

// ---------------------------------------------------------------------------
// Fused NNConv message+scatter:  agg[dst[e],o] += sum_C (h[e,k]*x[src,i]) * B[C,o]
// M=256 edges/block (4 waves x 64), N=64. K streamed in 2-chunk (128-row) LDS
// stages, double-buffered; B AND hv software-pipelined one full stage ahead so
// the compute loop has zero fresh-global dependencies.
template<int IN>
__global__ __launch_bounds__(256) void fused_msg(const f16* __restrict__ ht,
                                                 const f16* __restrict__ xf,
                                                 const f16* __restrict__ Bg,
                                                 const int* __restrict__ src,
                                                 const int* __restrict__ dst,
                                                 float* __restrict__ agg) {
    constexpr int INSH = (IN == 64) ? 6 : 5;
    constexpr int INK  = IN << 7;
    constexpr int LIM  = INK + IN;
    constexpr int NCH  = (LIM + 63) / 64;
    __shared__ f16 Bs[2][2 * 64 * BPAD];
    __shared__ int dst_l[256];
    const int t = threadIdx.x;
    const int w = t >> 6, lane = t & 63;
    const int m = lane & 15, q = lane >> 4;
    const int e0 = blockIdx.x * 256;
    const int cbeg = (NCH * (int)blockIdx.y) / KSPLIT;
    const int cend = (NCH * ((int)blockIdx.y + 1)) / KSPLIT;

    dst_l[t] = (e0 + t < N_EDGES) ? dst[e0 + t] : -1;

    // per-lane x fragments, fixed for whole K loop
    v8h xr[4][(IN == 64) ? 2 : 1];
    int eidx[4];
#pragma unroll
    for (int s = 0; s < 4; s++) {
        int e = e0 + w * 64 + s * 16 + m;
        eidx[s] = e < N_EDGES ? e : N_EDGES - 1;
        const f16* xrow = xf + (size_t)src[eidx[s]] * IN;
        xr[s][0] = *(const v8h*)(xrow + q * 8);
        if (IN == 64) xr[s][(IN == 64) ? 1 : 0] = *(const v8h*)(xrow + 32 + q * 8);
    }

    // B staging geometry: per slab, thread copies 32B: row so, segment sseg
    const int so = t >> 2, sseg = t & 3;
    const size_t goff = (size_t)so * 64 + sseg * 16;
    const int    loff = so * BPAD + sseg * 16;

    // ---- prologue: load stage 0 (B -> LDS buf0, hv -> hvc) ----
    f16 hvc[4][4], hvn[4][4];
    {
        uint4 r[4];
#pragma unroll
        for (int sl = 0; sl < 2; sl++) {
            int c = cbeg + sl; if (c > NCH - 1) c = NCH - 1;
            const uint4* gp = (const uint4*)(Bg + (size_t)c * 4096 + goff);
            r[sl * 2] = gp[0]; r[sl * 2 + 1] = gp[1];
        }
#pragma unroll
        for (int ph = 0; ph < 4; ph++) {
            const int c0 = ((cbeg + (ph >> 1)) << 6) + ((ph & 1) << 5);
            if (c0 < INK) {
                const f16* hp = ht + (size_t)(c0 >> INSH) * N_EDGES;
#pragma unroll
                for (int s = 0; s < 4; s++) hvc[ph][s] = hp[eidx[s]];
            } else {
#pragma unroll
                for (int s = 0; s < 4; s++) hvc[ph][s] = (f16)1.0f;
            }
        }
#pragma unroll
        for (int sl = 0; sl < 2; sl++) {
            *((uint4*)(&Bs[0][sl * 64 * BPAD + loff]))     = r[sl * 2];
            *((uint4*)(&Bs[0][sl * 64 * BPAD + loff + 8])) = r[sl * 2 + 1];
        }
    }
    __syncthreads();

    v4f acc[4][4] = {};
    int buf = 0;
    for (int cbase = cbeg; cbase < cend; cbase += 2) {
        // ---- prefetch stage+1 (B into regs, hv into hvn) ----
        uint4 r[4];
        const bool pf = (cbase + 2 < cend);
        if (pf) {
#pragma unroll
            for (int sl = 0; sl < 2; sl++) {
                int c = cbase + 2 + sl; if (c > NCH - 1) c = NCH - 1;
                const uint4* gp = (const uint4*)(Bg + (size_t)c * 4096 + goff);
                r[sl * 2] = gp[0]; r[sl * 2 + 1] = gp[1];
            }
#pragma unroll
            for (int ph = 0; ph < 4; ph++) {
                const int c0 = ((cbase + 2 + (ph >> 1)) << 6) + ((ph & 1) << 5);
                if (c0 < INK) {
                    const f16* hp = ht + (size_t)(c0 >> INSH) * N_EDGES;
#pragma unroll
                    for (int s = 0; s < 4; s++) hvn[ph][s] = hp[eidx[s]];
                } else {
#pragma unroll
                    for (int s = 0; s < 4; s++) hvn[ph][s] = (f16)1.0f;
                }
            }
        }
        // ---- compute current stage: LDS + registers only ----
        const f16* bb = Bs[buf];
#pragma unroll
        for (int ph = 0; ph < 4; ph++) {
            const int c = cbase + (ph >> 1);
            const int c0 = (c << 6) + ((ph & 1) << 5);
            if (c < cend && c0 < LIM) {
                const int xs = (IN == 64) ? (ph & 1) : 0;
                v8h bf[4];
#pragma unroll
                for (int tt = 0; tt < 4; tt++)
                    bf[tt] = *(const v8h*)(bb + (ph >> 1) * 64 * BPAD +
                                           (tt * 16 + m) * BPAD + (ph & 1) * 32 + q * 8);
#pragma unroll
                for (int s = 0; s < 4; s++) {
                    v8h af;
#pragma unroll
                    for (int j = 0; j < 8; j++) af[j] = xr[s][xs][j] * hvc[ph][s];
#pragma unroll
                    for (int tt = 0; tt < 4; tt++)
                        acc[s][tt] = __builtin_amdgcn_mfma_f32_16x16x32_f16(
                            af, bf[tt], acc[s][tt], 0, 0, 0);
                }
            }
        }
        // ---- publish prefetched B, rotate hv ----
        if (pf) {
#pragma unroll
            for (int sl = 0; sl < 2; sl++) {
                *((uint4*)(&Bs[buf ^ 1][sl * 64 * BPAD + loff]))     = r[sl * 2];
                *((uint4*)(&Bs[buf ^ 1][sl * 64 * BPAD + loff + 8])) = r[sl * 2 + 1];
            }
#pragma unroll
            for (int ph = 0; ph < 4; ph++)
#pragma unroll
                for (int s = 0; s < 4; s++) hvc[ph][s] = hvn[ph][s];
        }
        __syncthreads();
        buf ^= 1;
    }

    // epilogue: C/D layout col=lane&15, row=quad*4+reg
#pragma unroll
    for (int s = 0; s < 4; s++) {
        const int el = w * 64 + s * 16 + q * 4;
#pragma unroll
        for (int r = 0; r < 4; r++) {
            const int d = dst_l[el + r];
            if (d >= 0) {
#pragma unroll
                for (int tt = 0; tt < 4; tt++)
                    atomicAdd(&agg[(size_t)d * 64 + tt * 16 + m], acc[s][tt][r]);
            }
        }
    }
}

// ---------------------------------------------------------------------------
// pre[n,o] = agg[n,o] + sum_i x[n,i]*root[i,o] + bias[o]; accumulate BN stats.
__global__ __launch_bounds__(256) void pre_stats(const float* __restrict__ agg,
                                                 const float* __restrict__ x,
                                                 const float* __restrict__ root,
                                                 const float* __restrict__ bias,
                                                 float* __restrict__ pre,
                                                 float* __restrict__ stats,
                                                 int in, int inshift) {
    __shared__ float xs[4][64];
    __shared__ float lsum[64], lsq[64];
    const int o = threadIdx.x & 63, nl = threadIdx.x >> 6;
    if (threadIdx.x < 64) { lsum[threadIdx.x] = 0.f; lsq[threadIdx.x] = 0.f; }
    const float bo = bias[o];
    for (int n0 = blockIdx.x * 4; n0 < N_NODES; n0 += gridDim.x * 4) {
        __syncthreads();
        for (int idx = threadIdx.x; idx < (4 << inshift); idx += 256) {
            int r = idx >> inshift, i = idx & (in - 1);
            if (n0 + r < N_NODES) xs[r][i] = x[(size_t)(n0 + r) * in + i];
        }
        __syncthreads();
        int n = n0 + nl;
        if (n < N_NODES) {
            float acc = agg[(size_t)n * 64 + o] + bo;
#pragma unroll 8
            for (int i = 0; i < in; i++) acc += xs[nl][i] * root[i * 64 + o];
            pre[(size_t)n * 64 + o] = acc;
            atomicAdd(&lsum[o], acc);
            atomicAdd(&lsq[o], acc * acc);
        }
    }
    __syncthreads();
    if (threadIdx.x < 64) {
        atomicAdd(&stats[threadIdx.x], lsum[threadIdx.x]);
        atomicAdd(&stats[64 + threadIdx.x], lsq[threadIdx.x]);
    }
}

// ---------------------------------------------------------------------------
// BN (batch stats, biased var) + ReLU. mode 0: store xn. mode 1: segment-max pool.
__global__ __launch_bounds__(256) void bn_apply(const float* __restrict__ pre,
                                                const float* __restrict__ stats,
                                                const float* __restrict__ gamma,
                                                const float* __restrict__ beta,
                                                float* __restrict__ xn,
                                                const int* __restrict__ batch,
                                                float* __restrict__ pooled,
                                                int mode) {
    int idx = blockIdx.x * 256 + threadIdx.x;
    if (idx >= N_NODES * 64) return;
    const int o = idx & 63, n = idx >> 6;
    const float inv = 1.f / (float)N_NODES;
    float mu = stats[o] * inv;
    float var = stats[64 + o] * inv - mu * mu;
    float sc = gamma[o] * rsqrtf(var + EPS);
    float sh = beta[o] - mu * sc;
    float v = fmaxf(pre[idx] * sc + sh, 0.f);
    if (mode == 0) xn[idx] = v;
    else atomicMax((int*)&pooled[(size_t)batch[n] * 64 + o], __float_as_int(v));
}

// ---------------------------------------------------------------------------
// out[g] = pp_b2 + relu(cat(pooled[g],u[g]) @ pp_w1 + pp_b1) @ pp_w2
__global__ __launch_bounds__(64) void final_mlp(const float* __restrict__ pooled,
                                                const float* __restrict__ u,
                                                const float* __restrict__ w1,
                                                const float* __restrict__ b1,
                                                const float* __restrict__ w2,
                                                const float* __restrict__ b2,
                                                float* __restrict__ out) {
    const int g = blockIdx.x, t = threadIdx.x;
    float acc = b1[t];
#pragma unroll 8
    for (int i = 0; i < 64; i++) acc += pooled[g * 64 + i] * w1[i * 64 + t];
#pragma unroll
    for (int j = 0; j < GIN; j++) acc += u[g * GIN + j] * w1[(64 + j) * 64 + t];
    float hv = fmaxf(acc, 0.f) * w2[t];
#pragma unroll
    for (int off = 32; off > 0; off >>= 1) hv += __shfl_down(hv, off, 64);
    if (t == 0) out[g] = hv + b2[0];
}

// ---------------------------------------------------------------------------
extern "C" void kernel_launch(void* const* d_in, const int* in_sizes, int n_in,
                              void* d_out, int out_size, void* d_ws, size_t ws_size,
                              hipStream_t stream) {
    const float* x0      = (const float*)d_in[0];
    const int*   ei      = (const int*)d_in[1];
    const int*   src     = ei;
    const int*   dst     = ei + N_EDGES;
    const float* ea      = (const float*)d_in[2];
    const int*   batch   = (const int*)d_in[3];
    const float* u       = (const float*)d_in[4];
    const float* e0w1    = (const float*)d_in[5];
    const float* e0b1    = (const float*)d_in[6];
    const float* e0w2    = (const float*)d_in[7];
    const float* e0b2    = (const float*)d_in[8];
    const float* root0   = (const float*)d_in[9];
    const float* bias0   = (const float*)d_in[10];
    const float* gamma0  = (const float*)d_in[11];
    const float* beta0   = (const float*)d_in[12];
    const float* ew1     = (const float*)d_in[13];
    const float* eb1     = (const float*)d_in[14];
    const float* ew2     = (const float*)d_in[15];
    const float* eb2     = (const float*)d_in[16];
    const float* rootl   = (const float*)d_in[17];
    const float* biasl   = (const float*)d_in[18];
    const float* gammal  = (const float*)d_in[19];
    const float* betal   = (const float*)d_in[20];
    const float* pp_w1   = (const float*)d_in[21];
    const float* pp_b1   = (const float*)d_in[22];
    const float* pp_w2   = (const float*)d_in[23];
    const float* pp_b2   = (const float*)d_in[24];

    float* ws = (float*)d_ws;
    size_t off = 0;
    f16*   ht     = (f16*)(ws + off); off += (size_t)N_EDGES * KDIM / 2;
    f16*   xf     = (f16*)(ws + off); off += (size_t)N_NODES * 64 / 2;
    f16*   Bg     = (f16*)(ws + off); off += (size_t)129 * 4096 / 2;
    float* agg    = ws + off; off += (size_t)N_NODES * 64;
    float* xa     = ws + off; off += (size_t)N_NODES * 64;
    float* xb     = ws + off; off += (size_t)N_NODES * 64;
    float* stats  = ws + off; off += 256;
    float* pooled = ws + off; off += (size_t)NG * 64;

    hipMemsetAsync(pooled, 0, (size_t)NG * 64 * 4, stream);

    struct Layer {
        const float *w1, *b1, *w2, *b2, *root, *bias, *gamma, *beta, *xin;
        float* xout; int in, inshift, mode;
    };
    Layer L[4];
    L[0] = {e0w1, e0b1, e0w2, e0b2, root0, bias0, gamma0, beta0, x0, xa, IN0, 5, 0};
    for (int l = 0; l < 3; l++) {
        const float* xin  = (l == 0) ? xa : ((l == 1) ? xb : xa);
        float*       xout = (l == 0) ? xb : ((l == 1) ? xa : nullptr);
        L[l + 1] = {ew1 + (size_t)l * EDGE_IN * KDIM, eb1 + (size_t)l * KDIM,
                    ew2 + (size_t)l * KDIM * (HID * HID), eb2 + (size_t)l * (HID * HID),
                    rootl + (size_t)l * HID * HID, biasl + (size_t)l * HID,
                    gammal + (size_t)l * HID, betal + (size_t)l * HID,
                    xin, xout, HID, 6, (l == 2) ? 1 : 0};
    }

    const int eblocks = (N_EDGES + 255) / 256;               // 196
    const int ablocks = (N_NODES * 64 + 255) / 256;

    for (int l = 0; l < 4; l++) {
        const Layer& P = L[l];
        const int nch = (P.in * 129 + 63) / 64;              // 65 (in=32) / 129 (in=64)
        ht_kernel<<<eblocks, 256, 0, stream>>>(ea, P.w1, P.b1, ht);
        xconv<<<(N_NODES * P.in + 255) / 256, 256, 0, stream>>>(P.xin, xf, N_NODES * P.in);
        bconv<<<nch, 256, 0, stream>>>(P.w2, P.b2, Bg, P.in, P.inshift);
        hipMemsetAsync(agg, 0, (size_t)N_NODES * 64 * 4, stream);
        hipMemsetAsync(stats, 0, 128 * 4, stream);
        if (P.in == 64)
            fused_msg<64><<<dim3(eblocks, KSPLIT), 256, 0, stream>>>(ht, xf, Bg, src, dst, agg);
        else
            fused_msg<32><<<dim3(eblocks, KSPLIT), 256, 0, stream>>>(ht, xf, Bg, src, dst, agg);
        pre_stats<<<512, 256, 0, stream>>>(agg, P.xin, P.root, P.bias, agg, stats,
                                           P.in, P.inshift);
        bn_apply<<<ablocks, 256, 0, stream>>>(agg, stats, P.gamma, P.beta, P.xout,
                                              batch, pooled, P.mode);
    }
    final_mlp<<<NG, 64, 0, stream>>>(pooled, u, pp_w1, pp_b1, pp_w2, pp_b2,
                                     (float*)d_out);
}

// Round 7
// 937.234 us; speedup vs baseline: 1.2239x; 1.0991x over previous
//
#include <hip/hip_runtime.h>

#define N_NODES 10000
#define N_EDGES 50000
#define IN0     32
#define EDGE_IN 16
#define GIN     8
#define HID     64
#define NG      64
#define KDIM    128
#define EPS     1e-5f

typedef _Float16 f16;
typedef _Float16 v8h __attribute__((ext_vector_type(8)));
typedef float    v4f __attribute__((ext_vector_type(4)));

// ---------------------------------------------------------------------------
// ht[j][e] = f16(relu(ea[e]@w1[:,j] + b1[j]))  -- transposed for the fused GEMM
__global__ __launch_bounds__(256) void ht_kernel(const float* __restrict__ ea,
                                                 const float* __restrict__ w1,
                                                 const float* __restrict__ b1,
                                                 f16* __restrict__ ht) {
    __shared__ float eas[256][17];
    const int e0 = blockIdx.x * 256, t = threadIdx.x;
    for (int idx = t; idx < 256 * 16; idx += 256) {
        int r = idx >> 4, i = idx & 15;
        eas[r][i] = (e0 + r < N_EDGES) ? ea[(size_t)(e0 + r) * EDGE_IN + i] : 0.f;
    }
    __syncthreads();
    const int e = e0 + t;
#pragma unroll 1
    for (int j = 0; j < KDIM; j++) {
        float acc = b1[j];
#pragma unroll
        for (int i = 0; i < EDGE_IN; i++) acc += eas[t][i] * w1[i * KDIM + j];
        if (e < N_EDGES) ht[(size_t)j * N_EDGES + e] = (f16)fmaxf(acc, 0.f);
    }
}

// ---------------------------------------------------------------------------
// xf[idx] = f16(x[idx])
__global__ __launch_bounds__(256) void xconv(const float* __restrict__ x,
                                             f16* __restrict__ xf, int n) {
    int idx = blockIdx.x * 256 + threadIdx.x;
    if (idx < n) xf[idx] = (f16)x[idx];
}

// ---------------------------------------------------------------------------
// Bg[chunk][o][cc] = f16 of B[C=chunk*64+cc, o] where B[k*in+i, o]=w2[k][i*64+o],
// B[in*128+i, o]=b2[i*64+o], else 0.
__global__ __launch_bounds__(256) void bconv(const float* __restrict__ w2,
                                             const float* __restrict__ b2,
                                             f16* __restrict__ Bg,
                                             int in, int inshift) {
    const int chunk = blockIdx.x;
    const int inK = in << 7;
    const size_t base = (size_t)chunk * 4096;
    for (int l = threadIdx.x; l < 4096; l += 256) {
        int o = l >> 6, cc = l & 63;
        int C = (chunk << 6) + cc;
        float v = 0.f;
        if (C < inK) {
            int k = C >> inshift, i = C & (in - 1);
            v = w2[(size_t)k * (in << 6) + (i << 6) + o];
        } else if (C < inK + in) {
            v = b2[((C - inK) << 6) + o];
        }
        Bg[base + l] = (f16)v;
    }
}

// ---------------------------------------------------------------------------
// Fused NNConv message+scatter. Block = 64 edges, 4 waves = (K-half x o-half).
// Each wave streams its B fragments global->VGPR (L2-resident, ping-pong
// prefetch), NO barriers in the K-loop. K-halves merged via LDS, then one
// atomicAdd per (edge, o).
template<int IN>
__global__ __launch_bounds__(256, 3) void fused_msg(const f16* __restrict__ ht,
                                                    const f16* __restrict__ xf,
                                                    const f16* __restrict__ Bg,
                                                    const int* __restrict__ src,
                                                    const int* __restrict__ dst,
                                                    float* __restrict__ agg) {
    constexpr int INSH = (IN == 64) ? 6 : 5;
    constexpr int INK  = IN << 7;
    constexpr int LIM  = INK + IN;
    constexpr int NCH  = (LIM + 63) / 64;
    constexpr int NXR  = (IN == 64) ? 2 : 1;
    __shared__ float red[64 * 65];
    __shared__ int dst_l[64];
    const int t = threadIdx.x;
    const int w = t >> 6, lane = t & 63;
    const int m = lane & 15, q = lane >> 4;
    const int kh = w >> 1, oh = w & 1;
    const int e0 = blockIdx.x * 64;

    if (t < 64) dst_l[t] = (e0 + t < N_EDGES) ? dst[e0 + t] : -1;

    // per-lane x fragments (A rows = edges), fixed for whole K loop
    v8h xr[4][NXR];
    int eidx[4];
#pragma unroll
    for (int s = 0; s < 4; s++) {
        int e = e0 + s * 16 + m;
        eidx[s] = e < N_EDGES ? e : N_EDGES - 1;
        const f16* xrow = xf + (size_t)src[eidx[s]] * IN;
        xr[s][0] = *(const v8h*)(xrow + q * 8);
        if (IN == 64) xr[s][NXR - 1] = *(const v8h*)(xrow + 32 + q * 8);
    }

    const int cbeg = (NCH * kh) / 2;
    const int cend = (NCH * (kh + 1)) / 2;
    // lane-fixed base into a chunk: o = oh*32 + tt*16 + m, cc = ph*32 + q*8
    const f16* bbase = Bg + (size_t)((oh * 32 + m) * 64 + q * 8);

    auto loadB = [&](int c, v8h* b) {
        const f16* p = bbase + (size_t)c * 4096;
#pragma unroll
        for (int i = 0; i < 4; i++)   // i = ph*2 + tt
            b[i] = *(const v8h*)(p + (i & 1) * 1024 + (i >> 1) * 32);
    };
    auto loadH = [&](int c, f16 (*h)[4]) {
#pragma unroll
        for (int ph = 0; ph < 2; ph++) {
            if (IN == 64 && ph == 1) {
#pragma unroll
                for (int s = 0; s < 4; s++) h[1][s] = h[0][s];
            } else {
                const int c0 = (c << 6) + (ph << 5);
                if (c0 < INK) {
                    const f16* hp = ht + (size_t)(c0 >> INSH) * N_EDGES;
#pragma unroll
                    for (int s = 0; s < 4; s++) h[ph][s] = hp[eidx[s]];
                } else {
#pragma unroll
                    for (int s = 0; s < 4; s++) h[ph][s] = (f16)1.0f;
                }
            }
        }
    };

    v4f acc[4][2] = {};
    auto comp = [&](int c, const v8h* b, const f16 (*h)[4]) {
#pragma unroll
        for (int ph = 0; ph < 2; ph++) {
            const int c0 = (c << 6) + (ph << 5);
            if (c0 < LIM) {
                const int xs = (IN == 64) ? ph : 0;
#pragma unroll
                for (int s = 0; s < 4; s++) {
                    v8h af;
#pragma unroll
                    for (int j = 0; j < 8; j++) af[j] = xr[s][xs][j] * h[ph][s];
#pragma unroll
                    for (int tt = 0; tt < 2; tt++)
                        acc[s][tt] = __builtin_amdgcn_mfma_f32_16x16x32_f16(
                            af, b[ph * 2 + tt], acc[s][tt], 0, 0, 0);
                }
            }
        }
    };

    // ---- barrier-free K loop, ping-pong prefetch ----
    v8h bA[4], bB[4];
    f16 hA[2][4], hB[2][4];
    loadB(cbeg, bA); loadH(cbeg, hA);
    for (int c = cbeg; c < cend; c += 2) {
        if (c + 1 < cend) { loadB(c + 1, bB); loadH(c + 1, hB); }
        comp(c, bA, hA);
        if (c + 2 < cend) { loadB(c + 2, bA); loadH(c + 2, hA); }
        if (c + 1 < cend) comp(c + 1, bB, hB);
    }

    // ---- merge K-halves via LDS, then atomics (C/D: col=lane&15, row=q*4+r) ----
    __syncthreads();
    if (kh == 1) {
#pragma unroll
        for (int s = 0; s < 4; s++)
#pragma unroll
            for (int tt = 0; tt < 2; tt++)
#pragma unroll
                for (int r = 0; r < 4; r++)
                    red[(s * 16 + q * 4 + r) * 65 + oh * 32 + tt * 16 + m] = acc[s][tt][r];
    }
    __syncthreads();
    if (kh == 0) {
#pragma unroll
        for (int s = 0; s < 4; s++)
#pragma unroll
            for (int tt = 0; tt < 2; tt++)
#pragma unroll
                for (int r = 0; r < 4; r++) {
                    float v = acc[s][tt][r] +
                              red[(s * 16 + q * 4 + r) * 65 + oh * 32 + tt * 16 + m];
                    const int d = dst_l[s * 16 + q * 4 + r];
                    if (d >= 0)
                        atomicAdd(&agg[(size_t)d * 64 + oh * 32 + tt * 16 + m], v);
                }
    }
}

// ---------------------------------------------------------------------------
// pre[n,o] = agg[n,o] + sum_i x[n,i]*root[i,o] + bias[o]; accumulate BN stats.
__global__ __launch_bounds__(256) void pre_stats(const float* __restrict__ agg,
                                                 const float* __restrict__ x,
                                                 const float* __restrict__ root,
                                                 const float* __restrict__ bias,
                                                 float* __restrict__ pre,
                                                 float* __restrict__ stats,
                                                 int in, int inshift) {
    __shared__ float xs[4][64];
    __shared__ float lsum[64], lsq[64];
    const int o = threadIdx.x & 63, nl = threadIdx.x >> 6;
    if (threadIdx.x < 64) { lsum[threadIdx.x] = 0.f; lsq[threadIdx.x] = 0.f; }
    const float bo = bias[o];
    for (int n0 = blockIdx.x * 4; n0 < N_NODES; n0 += gridDim.x * 4) {
        __syncthreads();
        for (int idx = threadIdx.x; idx < (4 << inshift); idx += 256) {
            int r = idx >> inshift, i = idx & (in - 1);
            if (n0 + r < N_NODES) xs[r][i] = x[(size_t)(n0 + r) * in + i];
        }
        __syncthreads();
        int n = n0 + nl;
        if (n < N_NODES) {
            float acc = agg[(size_t)n * 64 + o] + bo;
#pragma unroll 8
            for (int i = 0; i < in; i++) acc += xs[nl][i] * root[i * 64 + o];
            pre[(size_t)n * 64 + o] = acc;
            atomicAdd(&lsum[o], acc);
            atomicAdd(&lsq[o], acc * acc);
        }
    }
    __syncthreads();
    if (threadIdx.x < 64) {
        atomicAdd(&stats[threadIdx.x], lsum[threadIdx.x]);
        atomicAdd(&stats[64 + threadIdx.x], lsq[threadIdx.x]);
    }
}

// ---------------------------------------------------------------------------
// BN (batch stats, biased var) + ReLU. mode 0: store xn. mode 1: segment-max pool.
__global__ __launch_bounds__(256) void bn_apply(const float* __restrict__ pre,
                                                const float* __restrict__ stats,
                                                const float* __restrict__ gamma,
                                                const float* __restrict__ beta,
                                                float* __restrict__ xn,
                                                const int* __restrict__ batch,
                                                float* __restrict__ pooled,
                                                int mode) {
    int idx = blockIdx.x * 256 + threadIdx.x;
    if (idx >= N_NODES * 64) return;
    const int o = idx & 63, n = idx >> 6;
    const float inv = 1.f / (float)N_NODES;
    float mu = stats[o] * inv;
    float var = stats[64 + o] * inv - mu * mu;
    float sc = gamma[o] * rsqrtf(var + EPS);
    float sh = beta[o] - mu * sc;
    float v = fmaxf(pre[idx] * sc + sh, 0.f);
    if (mode == 0) xn[idx] = v;
    else atomicMax((int*)&pooled[(size_t)batch[n] * 64 + o], __float_as_int(v));
}

// ---------------------------------------------------------------------------
// out[g] = pp_b2 + relu(cat(pooled[g],u[g]) @ pp_w1 + pp_b1) @ pp_w2
__global__ __launch_bounds__(64) void final_mlp(const float* __restrict__ pooled,
                                                const float* __restrict__ u,
                                                const float* __restrict__ w1,
                                                const float* __restrict__ b1,
                                                const float* __restrict__ w2,
                                                const float* __restrict__ b2,
                                                float* __restrict__ out) {
    const int g = blockIdx.x, t = threadIdx.x;
    float acc = b1[t];
#pragma unroll 8
    for (int i = 0; i < 64; i++) acc += pooled[g * 64 + i] * w1[i * 64 + t];
#pragma unroll
    for (int j = 0; j < GIN; j++) acc += u[g * GIN + j] * w1[(64 + j) * 64 + t];
    float hv = fmaxf(acc, 0.f) * w2[t];
#pragma unroll
    for (int off = 32; off > 0; off >>= 1) hv += __shfl_down(hv, off, 64);
    if (t == 0) out[g] = hv + b2[0];
}

// ---------------------------------------------------------------------------
extern "C" void kernel_launch(void* const* d_in, const int* in_sizes, int n_in,
                              void* d_out, int out_size, void* d_ws, size_t ws_size,
                              hipStream_t stream) {
    const float* x0      = (const float*)d_in[0];
    const int*   ei      = (const int*)d_in[1];
    const int*   src     = ei;
    const int*   dst     = ei + N_EDGES;
    const float* ea      = (const float*)d_in[2];
    const int*   batch   = (const int*)d_in[3];
    const float* u       = (const float*)d_in[4];
    const float* e0w1    = (const float*)d_in[5];
    const float* e0b1    = (const float*)d_in[6];
    const float* e0w2    = (const float*)d_in[7];
    const float* e0b2    = (const float*)d_in[8];
    const float* root0   = (const float*)d_in[9];
    const float* bias0   = (const float*)d_in[10];
    const float* gamma0  = (const float*)d_in[11];
    const float* beta0   = (const float*)d_in[12];
    const float* ew1     = (const float*)d_in[13];
    const float* eb1     = (const float*)d_in[14];
    const float* ew2     = (const float*)d_in[15];
    const float* eb2     = (const float*)d_in[16];
    const float* rootl   = (const float*)d_in[17];
    const float* biasl   = (const float*)d_in[18];
    const float* gammal  = (const float*)d_in[19];
    const float* betal   = (const float*)d_in[20];
    const float* pp_w1   = (const float*)d_in[21];
    const float* pp_b1   = (const float*)d_in[22];
    const float* pp_w2   = (const float*)d_in[23];
    const float* pp_b2   = (const float*)d_in[24];

    float* ws = (float*)d_ws;
    size_t off = 0;
    f16*   ht     = (f16*)(ws + off); off += (size_t)N_EDGES * KDIM / 2;
    f16*   xf     = (f16*)(ws + off); off += (size_t)N_NODES * 64 / 2;
    f16*   Bg     = (f16*)(ws + off); off += (size_t)129 * 4096 / 2;
    float* agg    = ws + off; off += (size_t)N_NODES * 64;
    float* xa     = ws + off; off += (size_t)N_NODES * 64;
    float* xb     = ws + off; off += (size_t)N_NODES * 64;
    float* stats  = ws + off; off += 256;
    float* pooled = ws + off; off += (size_t)NG * 64;

    hipMemsetAsync(pooled, 0, (size_t)NG * 64 * 4, stream);

    struct Layer {
        const float *w1, *b1, *w2, *b2, *root, *bias, *gamma, *beta, *xin;
        float* xout; int in, inshift, mode;
    };
    Layer L[4];
    L[0] = {e0w1, e0b1, e0w2, e0b2, root0, bias0, gamma0, beta0, x0, xa, IN0, 5, 0};
    for (int l = 0; l < 3; l++) {
        const float* xin  = (l == 0) ? xa : ((l == 1) ? xb : xa);
        float*       xout = (l == 0) ? xb : ((l == 1) ? xa : nullptr);
        L[l + 1] = {ew1 + (size_t)l * EDGE_IN * KDIM, eb1 + (size_t)l * KDIM,
                    ew2 + (size_t)l * KDIM * (HID * HID), eb2 + (size_t)l * (HID * HID),
                    rootl + (size_t)l * HID * HID, biasl + (size_t)l * HID,
                    gammal + (size_t)l * HID, betal + (size_t)l * HID,
                    xin, xout, HID, 6, (l == 2) ? 1 : 0};
    }

    const int hblocks = (N_EDGES + 255) / 256;               // 196
    const int fblocks = (N_EDGES + 63) / 64;                 // 782
    const int ablocks = (N_NODES * 64 + 255) / 256;

    for (int l = 0; l < 4; l++) {
        const Layer& P = L[l];
        const int nch = (P.in * 129 + 63) / 64;              // 65 (in=32) / 129 (in=64)
        ht_kernel<<<hblocks, 256, 0, stream>>>(ea, P.w1, P.b1, ht);
        xconv<<<(N_NODES * P.in + 255) / 256, 256, 0, stream>>>(P.xin, xf, N_NODES * P.in);
        bconv<<<nch, 256, 0, stream>>>(P.w2, P.b2, Bg, P.in, P.inshift);
        hipMemsetAsync(agg, 0, (size_t)N_NODES * 64 * 4, stream);
        hipMemsetAsync(stats, 0, 128 * 4, stream);
        if (P.in == 64)
            fused_msg<64><<<fblocks, 256, 0, stream>>>(ht, xf, Bg, src, dst, agg);
        else
            fused_msg<32><<<fblocks, 256, 0, stream>>>(ht, xf, Bg, src, dst, agg);
        pre_stats<<<512, 256, 0, stream>>>(agg, P.xin, P.root, P.bias, agg, stats,
                                           P.in, P.inshift);
        bn_apply<<<ablocks, 256, 0, stream>>>(agg, stats, P.gamma, P.beta, P.xout,
                                              batch, pooled, P.mode);
    }
    final_mlp<<<NG, 64, 0, stream>>>(pooled, u, pp_w1, pp_b1, pp_w2, pp_b2,
                                     (float*)d_out);
}